// Round 12
// baseline (169.235 us; speedup 1.0000x reference)
//
#include <hip/hip_runtime.h>

#define TS 2048   // seq len
#define DM 1024   // d_model
#define KD 64     // k
#define NB 4      // batch

// ---------- workspace layout (float offsets) ----------
// WT_hi [192][1024] ushort : rows 0-63 Wq^T, 64-127 Wk^T, 128-191 Wv^T (bf16 hi)
// WT_lo [192][1024] ushort : bf16 residual (lo)
// bcomb [192] f32          : bq | bk | bv
// Qg    [8192][64] f32     : Q-only (k_chunkred -> k_inter)
// P     [4][8192][192] f32 : split-K partials (k_qkv -> k_chunkred)
// Pf    [16][128][1024] f32: fold partials (k_prep -> k_fred), overlays P front
// St    [4][64][64][64] f32: exclusive chunk-prefix (k_scan -> k_inter),
//                            overlays dead P region (P consumed by k_chunkred)
// O     [4][64][64][64] f32: per-chunk outer sums (k_chunkred -> k_scan)
// Yb    [8192][64] f32     : intra-chunk Y (k_chunkred -> k_inter)
// WoT_hi/lo [1024][64] ushort : Wo^T bf16 hi/lo  (k_fred -> k_out)
// Yf_hi/lo  [8192][64] ushort : final Y bf16 hi/lo (k_inter -> k_out)
#define WTH_OFF 0
#define WTL_OFF 98304
#define BC_OFF  196608
#define QG_OFF  196864
#define P_OFF   1769728
#define PF_OFF  (P_OFF)
#define ST_OFF  (P_OFF)
#define O_OFF   8061184
#define YB_OFF  9109760
#define WOTH_OFF 9634048
#define WOTL_OFF 9666816
#define YFH_OFF  9699584
#define YFL_OFF  9961728

typedef __attribute__((ext_vector_type(8))) short bf16x8;
typedef __attribute__((ext_vector_type(4))) float f32x4;

__device__ __forceinline__ ushort f2bf(float f) {
  unsigned u = __float_as_uint(f);
  unsigned r = u + 0x7FFFu + ((u >> 16) & 1u);
  return (ushort)(r >> 16);
}
__device__ __forceinline__ float bf2f(ushort h) {
  return __uint_as_float(((unsigned)h) << 16);
}

// ---------------- A1: split-K MFMA fold partials ----------------
__global__ __launch_bounds__(256) void k_prep(
    const float* __restrict__ W_pre, const float* __restrict__ Qf,
    const float* __restrict__ Kf, float* __restrict__ Pf) {
  const int d0 = blockIdx.x * 64;
  const int f = blockIdx.y;
  const int ks = blockIdx.z;
  const float* __restrict__ F = f ? Kf : Qf;
  const int tid = threadIdx.x;
  const int wave = tid >> 6, lane = tid & 63;
  const int quad = lane >> 4, l15 = lane & 15;
  __shared__ ushort As[64 * 72];
  __shared__ ushort Bs[64 * 72];
  f32x4 acc[4];
#pragma unroll
  for (int nt = 0; nt < 4; ++nt) acc[nt] = (f32x4){0.f, 0.f, 0.f, 0.f};

  const int ra = tid >> 3;
  const int c4 = (tid & 7) * 4;
  float4 aw[2];
  float bw[8];
  int t0 = ks * 128;
#pragma unroll
  for (int i = 0; i < 2; ++i)
    aw[i] = *(const float4*)&W_pre[(size_t)(d0 + i * 32 + ra) * TS + t0 + c4];
#pragma unroll
  for (int h = 0; h < 2; ++h)
#pragma unroll
    for (int u = 0; u < 4; ++u)
      bw[h * 4 + u] = F[(size_t)(t0 + (wave + 4 * h) * 4 + u) * KD + lane];

  for (int step = 0; step < 4; ++step) {
    __syncthreads();
#pragma unroll
    for (int i = 0; i < 2; ++i) {
      const int r = i * 32 + ra;
      const float4 v = aw[i];
      const ushort h0 = f2bf(v.x), h1 = f2bf(v.y), h2 = f2bf(v.z), h3 = f2bf(v.w);
      *(ushort4*)&As[r * 72 + c4] = make_ushort4(h0, h1, h2, h3);
      *(ushort4*)&As[r * 72 + 32 + c4] = make_ushort4(
          f2bf(v.x - bf2f(h0)), f2bf(v.y - bf2f(h1)),
          f2bf(v.z - bf2f(h2)), f2bf(v.w - bf2f(h3)));
    }
#pragma unroll
    for (int h = 0; h < 2; ++h) {
      const int gg = wave + 4 * h;
      ushort hh[4], ll[4];
#pragma unroll
      for (int u = 0; u < 4; ++u) {
        hh[u] = f2bf(bw[h * 4 + u]);
        ll[u] = f2bf(bw[h * 4 + u] - bf2f(hh[u]));
      }
      *(ushort4*)&Bs[lane * 72 + gg * 4] = make_ushort4(hh[0], hh[1], hh[2], hh[3]);
      *(ushort4*)&Bs[lane * 72 + 32 + gg * 4] = make_ushort4(ll[0], ll[1], ll[2], ll[3]);
    }
    __syncthreads();
    if (step < 3) {
      const int t1 = t0 + 32;
#pragma unroll
      for (int i = 0; i < 2; ++i)
        aw[i] = *(const float4*)&W_pre[(size_t)(d0 + i * 32 + ra) * TS + t1 + c4];
#pragma unroll
      for (int h = 0; h < 2; ++h)
#pragma unroll
        for (int u = 0; u < 4; ++u)
          bw[h * 4 + u] = F[(size_t)(t1 + (wave + 4 * h) * 4 + u) * KD + lane];
    }
    const ushort* ap = &As[(wave * 16 + l15) * 72 + quad * 8];
    const bf16x8 a_h = *(const bf16x8*)ap;
    const bf16x8 a_l = *(const bf16x8*)(ap + 32);
#pragma unroll
    for (int nt = 0; nt < 4; ++nt) {
      const ushort* bp = &Bs[(nt * 16 + l15) * 72 + quad * 8];
      const bf16x8 b_h = *(const bf16x8*)bp;
      const bf16x8 b_l = *(const bf16x8*)(bp + 32);
      acc[nt] = __builtin_amdgcn_mfma_f32_16x16x32_bf16(a_h, b_h, acc[nt], 0, 0, 0);
      acc[nt] = __builtin_amdgcn_mfma_f32_16x16x32_bf16(a_h, b_l, acc[nt], 0, 0, 0);
      acc[nt] = __builtin_amdgcn_mfma_f32_16x16x32_bf16(a_l, b_h, acc[nt], 0, 0, 0);
    }
    t0 += 32;
  }
#pragma unroll
  for (int nt = 0; nt < 4; ++nt) {
    const int n = f * 64 + nt * 16 + l15;
#pragma unroll
    for (int r = 0; r < 4; ++r) {
      const int d = d0 + wave * 16 + quad * 4 + r;
      Pf[((size_t)ks * 128 + n) * DM + d] = acc[nt][r];
    }
  }
}

// ---------------- A2: reduce fold partials -> WT hi/lo; Wv transpose; bias;
// ----------------     Wo transpose -> WoT hi/lo ----------------
__global__ __launch_bounds__(256) void k_fred(
    const float* __restrict__ Pf, const float* __restrict__ Wv,
    const float* __restrict__ b_pre, const float* __restrict__ Qf,
    const float* __restrict__ Kf, const float* __restrict__ bv,
    const float* __restrict__ Wo,
    ushort* __restrict__ WT_hi, ushort* __restrict__ WT_lo,
    float* __restrict__ bcomb,
    ushort* __restrict__ WoT_hi, ushort* __restrict__ WoT_lo) {
  const int bx = blockIdx.x;
  const int tid = threadIdx.x;
  if (bx < 32) {
    const int n0 = bx * 4;
    const int d4 = tid * 4;
#pragma unroll
    for (int j = 0; j < 4; ++j) {
      const int n = n0 + j;
      float4 s = {0.f, 0.f, 0.f, 0.f};
#pragma unroll
      for (int ks = 0; ks < 16; ++ks) {
        const float4 v = *(const float4*)&Pf[((size_t)ks * 128 + n) * DM + d4];
        s.x += v.x; s.y += v.y; s.z += v.z; s.w += v.w;
      }
      const ushort h0 = f2bf(s.x), h1 = f2bf(s.y), h2 = f2bf(s.z), h3 = f2bf(s.w);
      *(ushort4*)&WT_hi[(size_t)n * DM + d4] = make_ushort4(h0, h1, h2, h3);
      *(ushort4*)&WT_lo[(size_t)n * DM + d4] = make_ushort4(
          f2bf(s.x - bf2f(h0)), f2bf(s.y - bf2f(h1)),
          f2bf(s.z - bf2f(h2)), f2bf(s.w - bf2f(h3)));
    }
    const float* __restrict__ F = (n0 < 64) ? Qf : Kf;
    const int c0 = n0 & 63;
    __shared__ float bred[4][256];
    float p[4] = {0.f, 0.f, 0.f, 0.f};
#pragma unroll
    for (int u = 0; u < 8; ++u) {
      const int t = tid * 8 + u;
      const float bp = b_pre[t];
#pragma unroll
      for (int j = 0; j < 4; ++j) p[j] += bp * F[(size_t)t * KD + c0 + j];
    }
#pragma unroll
    for (int j = 0; j < 4; ++j) bred[j][tid] = p[j];
    __syncthreads();
    for (int s = 128; s > 0; s >>= 1) {
      if (tid < s) {
#pragma unroll
        for (int j = 0; j < 4; ++j) bred[j][tid] += bred[j][tid + s];
      }
      __syncthreads();
    }
    if (tid < 4) bcomb[n0 + tid] = bred[tid][0];
  } else if (bx < 48) {
    const int n0 = 128 + (bx - 32) * 4;
    const int d4 = tid * 4;
#pragma unroll
    for (int j = 0; j < 4; ++j) {
      const int c = n0 - 128 + j;
      float v[4];
#pragma unroll
      for (int i = 0; i < 4; ++i) v[i] = Wv[(size_t)(d4 + i) * KD + c];
      const ushort h0 = f2bf(v[0]), h1 = f2bf(v[1]), h2 = f2bf(v[2]), h3 = f2bf(v[3]);
      *(ushort4*)&WT_hi[(size_t)(n0 + j) * DM + d4] = make_ushort4(h0, h1, h2, h3);
      *(ushort4*)&WT_lo[(size_t)(n0 + j) * DM + d4] = make_ushort4(
          f2bf(v[0] - bf2f(h0)), f2bf(v[1] - bf2f(h1)),
          f2bf(v[2] - bf2f(h2)), f2bf(v[3] - bf2f(h3)));
    }
    if (tid < 4) bcomb[n0 + tid] = bv[n0 - 128 + tid];
  } else {
    // Wo [64][1024] -> WoT [1024][64] bf16 hi/lo
    const int d0 = (bx - 48) * 64;
    const int d = d0 + (tid >> 2);
    const int k0 = (tid & 3) * 16;
#pragma unroll
    for (int u = 0; u < 16; ++u) {
      const int k = k0 + u;
      const float v = Wo[(size_t)k * DM + d];
      const ushort h = f2bf(v);
      WoT_hi[(size_t)d * KD + k] = h;
      WoT_lo[(size_t)d * KD + k] = f2bf(v - bf2f(h));
    }
  }
}

// ---------------- B: split-K MFMA bf16x3 GEMM  P[ks] = x[:, ks*256:+256] @ W ----------------
// (R8/R10-verified: 64-row tile, 512 threads / 8 waves, LDS-transpose epilogue)
__global__ __launch_bounds__(512) void k_qkv(
    const float* __restrict__ x, const ushort* __restrict__ WT_hi,
    const ushort* __restrict__ WT_lo, float* __restrict__ P) {
  const int row0 = blockIdx.x * 64;
  const int ks = blockIdx.y;
  const int tid = threadIdx.x;
  const int wave = tid >> 6, lane = tid & 63;
  const int quad = lane >> 4, l15 = lane & 15;
  const int wm = wave >> 2;   // 0..1 : 32-row half
  const int wn = wave & 3;    // 0..3 : 48-col slice
  const int n0 = wn * 48;
  __shared__ ushort As[64 * 72];
  __shared__ ushort Bs[192 * 72];
  __shared__ float Cs[16][196];
  f32x4 acc[2][3];
#pragma unroll
  for (int mt = 0; mt < 2; ++mt)
#pragma unroll
    for (int nt = 0; nt < 3; ++nt) acc[mt][nt] = (f32x4){0.f, 0.f, 0.f, 0.f};

  for (int step = 0; step < 8; ++step) {
    const int kk = ks * 256 + step * 32;
    __syncthreads();
    {
      // A-tile: 64 rows x 32 cols = 512 float4, one per thread
      const int r = tid >> 3, c4 = (tid & 7) * 4;
      const float4 v = *(const float4*)&x[(size_t)(row0 + r) * DM + kk + c4];
      const ushort h0 = f2bf(v.x), h1 = f2bf(v.y), h2 = f2bf(v.z), h3 = f2bf(v.w);
      *(ushort4*)&As[r * 72 + c4] = make_ushort4(h0, h1, h2, h3);
      *(ushort4*)&As[r * 72 + 32 + c4] = make_ushort4(
          f2bf(v.x - bf2f(h0)), f2bf(v.y - bf2f(h1)),
          f2bf(v.z - bf2f(h2)), f2bf(v.w - bf2f(h3)));
    }
#pragma unroll
    for (int i = 0; i < 3; ++i) {
      // B-tile: 1536 float4 over 512 threads
      const int idx = i * 512 + tid;
      const int half = idx >= 768;
      const int j = half ? idx - 768 : idx;
      const int n = j >> 2, ch = j & 3;
      const ushort* src = (half ? WT_lo : WT_hi) + (size_t)n * DM + kk + ch * 8;
      *(float4*)&Bs[n * 72 + half * 32 + ch * 8] = *(const float4*)src;
    }
    __syncthreads();
    bf16x8 a_h[2], a_l[2], b_h[3], b_l[3];
#pragma unroll
    for (int mt = 0; mt < 2; ++mt) {
      const ushort* p = &As[(wm * 32 + mt * 16 + l15) * 72 + quad * 8];
      a_h[mt] = *(const bf16x8*)p;
      a_l[mt] = *(const bf16x8*)(p + 32);
    }
#pragma unroll
    for (int nt = 0; nt < 3; ++nt) {
      const ushort* p = &Bs[(n0 + nt * 16 + l15) * 72 + quad * 8];
      b_h[nt] = *(const bf16x8*)p;
      b_l[nt] = *(const bf16x8*)(p + 32);
    }
#pragma unroll
    for (int mt = 0; mt < 2; ++mt)
#pragma unroll
      for (int nt = 0; nt < 3; ++nt) {
        acc[mt][nt] = __builtin_amdgcn_mfma_f32_16x16x32_bf16(a_h[mt], b_h[nt], acc[mt][nt], 0, 0, 0);
        acc[mt][nt] = __builtin_amdgcn_mfma_f32_16x16x32_bf16(a_h[mt], b_l[nt], acc[mt][nt], 0, 0, 0);
        acc[mt][nt] = __builtin_amdgcn_mfma_f32_16x16x32_bf16(a_l[mt], b_h[nt], acc[mt][nt], 0, 0, 0);
      }
  }
  // LDS-transpose epilogue: per 16-row chunk (owned by wave-half wm==mtg>>1),
  // stage acc -> Cs, then all 512 threads write full 768 B contiguous rows.
  float* Pp = P + (size_t)ks * TS * NB * 192;
#pragma unroll
  for (int mtg = 0; mtg < 4; ++mtg) {
    __syncthreads();
    if (wm == (mtg >> 1)) {
      const int mt = mtg & 1;
#pragma unroll
      for (int nt = 0; nt < 3; ++nt)
#pragma unroll
        for (int r = 0; r < 4; ++r)
          Cs[quad * 4 + r][n0 + nt * 16 + l15] = acc[mt][nt][r];
    }
    __syncthreads();
    // 16 rows x 48 float4 = 768 float4 over 512 threads
#pragma unroll
    for (int it = 0; it < 2; ++it) {
      const int idx = it * 512 + tid;
      if (idx < 768) {
        const int r = idx / 48, c4 = (idx % 48) * 4;
        *(float4*)&Pp[(size_t)(row0 + mtg * 16 + r) * 192 + c4] =
            *(const float4*)&Cs[r][c4];
      }
    }
  }
}

// ---------------- C1: fused split-K reduce + per-chunk intra + outer sums ----------------
// (R11-verified: 512 threads, Ss/Yb chain on waves 0-3, O chain on waves 4-7)
__global__ __launch_bounds__(512) void k_chunkred(
    const float* __restrict__ P, const float* __restrict__ bcomb,
    const float* __restrict__ decay, float* __restrict__ Qg,
    float* __restrict__ Yb, float* __restrict__ O) {
  const int c = blockIdx.x;
  const int b = blockIdx.y;
  const int s0 = c * 32;
  const int tid = threadIdx.x;
  __shared__ float Qs[32][68], Ks[32][68], Vs[32][68];
  __shared__ float Ss[32][36];
  __shared__ float dec[32];
  const size_t NTOT = (size_t)TS * NB * 192;

  for (int idx = tid; idx < 32 * 48; idx += 512) {
    const int r = idx / 48, cq = (idx % 48) * 4;
    const size_t g = (size_t)(b * TS + s0 + r) * 192 + cq;
    float4 a = *(const float4*)&P[g];
    const float4 b2 = *(const float4*)&P[NTOT + g];
    const float4 c2 = *(const float4*)&P[2 * NTOT + g];
    const float4 d2 = *(const float4*)&P[3 * NTOT + g];
    const float4 bi = *(const float4*)&bcomb[cq];
    a.x += b2.x + c2.x + d2.x + bi.x;
    a.y += b2.y + c2.y + d2.y + bi.y;
    a.z += b2.z + c2.z + d2.z + bi.z;
    a.w += b2.w + c2.w + d2.w + bi.w;
    if (cq < 64) {
      *(float4*)&Qs[r][cq] = a;
      *(float4*)&Qg[(size_t)(b * TS + s0 + r) * KD + cq] = a;
    } else if (cq < 128) {
      *(float4*)&Ks[r][cq - 64] = a;
    } else {
      *(float4*)&Vs[r][cq - 128] = a;
    }
  }
  if (tid < 32) dec[tid] = decay[s0 + tid];
  __syncthreads();

  float o[4][4];
  if (tid < 256) {
    const int sc = (tid & 15) * 2;
    const int tr = (tid >> 4) * 2;
    float a00 = 0.f, a01 = 0.f, a10 = 0.f, a11 = 0.f;
#pragma unroll
    for (int k = 0; k < 64; k += 4) {
      const float4 q0 = *(const float4*)&Qs[tr][k];
      const float4 q1 = *(const float4*)&Qs[tr + 1][k];
      const float4 v0 = *(const float4*)&Vs[sc][k];
      const float4 v1 = *(const float4*)&Vs[sc + 1][k];
      a00 += q0.x * v0.x + q0.y * v0.y + q0.z * v0.z + q0.w * v0.w;
      a01 += q0.x * v1.x + q0.y * v1.y + q0.z * v1.z + q0.w * v1.w;
      a10 += q1.x * v0.x + q1.y * v0.y + q1.z * v0.z + q1.w * v0.w;
      a11 += q1.x * v1.x + q1.y * v1.y + q1.z * v1.z + q1.w * v1.w;
    }
    const float d0 = dec[sc], d1 = dec[sc + 1];
    Ss[tr][sc]         = (sc     <= tr)     ? a00 * d0 : 0.f;
    Ss[tr][sc + 1]     = (sc + 1 <= tr)     ? a01 * d1 : 0.f;
    Ss[tr + 1][sc]     = (sc     <= tr + 1) ? a10 * d0 : 0.f;
    Ss[tr + 1][sc + 1] = (sc + 1 <= tr + 1) ? a11 * d1 : 0.f;
  } else {
    const int t2 = tid - 256;
#pragma unroll
    for (int i = 0; i < 4; ++i)
#pragma unroll
      for (int j = 0; j < 4; ++j) o[i][j] = 0.f;
    const int kx = (t2 & 15) * 4;
    const int nx = (t2 >> 4) * 4;
#pragma unroll
    for (int s = 0; s < 32; ++s) {
      const float ds = dec[s];
      float4 v4 = *(const float4*)&Vs[s][kx];
      const float4 k4 = *(const float4*)&Ks[s][nx];
      v4.x *= ds; v4.y *= ds; v4.z *= ds; v4.w *= ds;
      o[0][0] += v4.x * k4.x; o[0][1] += v4.x * k4.y; o[0][2] += v4.x * k4.z; o[0][3] += v4.x * k4.w;
      o[1][0] += v4.y * k4.x; o[1][1] += v4.y * k4.y; o[1][2] += v4.y * k4.z; o[1][3] += v4.y * k4.w;
      o[2][0] += v4.z * k4.x; o[2][1] += v4.z * k4.y; o[2][2] += v4.z * k4.z; o[2][3] += v4.z * k4.w;
      o[3][0] += v4.w * k4.x; o[3][1] += v4.w * k4.y; o[3][2] += v4.w * k4.z; o[3][3] += v4.w * k4.w;
    }
  }
  __syncthreads();

  if (tid < 256) {
    const int nx = (tid & 15) * 4;
    const int tr = (tid >> 4) * 2;
    float y0[4] = {0.f, 0.f, 0.f, 0.f};
    float y1[4] = {0.f, 0.f, 0.f, 0.f};
#pragma unroll
    for (int s = 0; s < 32; s += 4) {
      const float4 sa = *(const float4*)&Ss[tr][s];
      const float4 sb = *(const float4*)&Ss[tr + 1][s];
#pragma unroll
      for (int u = 0; u < 4; ++u) {
        const float4 k4 = *(const float4*)&Ks[s + u][nx];
        const float su0 = (u == 0) ? sa.x : (u == 1) ? sa.y : (u == 2) ? sa.z : sa.w;
        const float su1 = (u == 0) ? sb.x : (u == 1) ? sb.y : (u == 2) ? sb.z : sb.w;
        y0[0] += su0 * k4.x; y0[1] += su0 * k4.y; y0[2] += su0 * k4.z; y0[3] += su0 * k4.w;
        y1[0] += su1 * k4.x; y1[1] += su1 * k4.y; y1[2] += su1 * k4.z; y1[3] += su1 * k4.w;
      }
    }
    float4 w0, w1;
    w0.x = y0[0]; w0.y = y0[1]; w0.z = y0[2]; w0.w = y0[3];
    w1.x = y1[0]; w1.y = y1[1]; w1.z = y1[2]; w1.w = y1[3];
    *(float4*)&Yb[(size_t)(b * TS + s0 + tr) * KD + nx] = w0;
    *(float4*)&Yb[(size_t)(b * TS + s0 + tr + 1) * KD + nx] = w1;
  } else {
    const int t2 = tid - 256;
    const int kx = (t2 & 15) * 4;
    const int nx = (t2 >> 4) * 4;
    const size_t base = ((size_t)(b * 64 + c) * 64) * 64;
#pragma unroll
    for (int i = 0; i < 4; ++i) {
      float4 w;
      w.x = o[i][0]; w.y = o[i][1]; w.z = o[i][2]; w.w = o[i][3];
      *(float4*)&O[base + (size_t)(kx + i) * 64 + nx] = w;
    }
  }
}

// ---------------- C2: exclusive prefix over chunks (O -> St) ----------------
__global__ __launch_bounds__(64) void k_scan(const float* __restrict__ O,
                                             float* __restrict__ St) {
  const int e4 = (blockIdx.x * 64 + threadIdx.x) * 4;
  const int b = blockIdx.y;
  const float* op = O + (size_t)b * 64 * 4096 + e4;
  float* sp = St + (size_t)b * 64 * 4096 + e4;
  float4 run = {0.f, 0.f, 0.f, 0.f};
#pragma unroll
  for (int cg = 0; cg < 8; ++cg) {
    float4 v[8];
#pragma unroll
    for (int u = 0; u < 8; ++u)
      v[u] = *(const float4*)&op[(size_t)(cg * 8 + u) * 4096];
#pragma unroll
    for (int u = 0; u < 8; ++u) {
      *(float4*)&sp[(size_t)(cg * 8 + u) * 4096] = run;
      run.x += v[u].x; run.y += v[u].y; run.z += v[u].z; run.w += v[u].w;
    }
  }
}

// ---------------- C3: inter-chunk attention, emit Y as bf16 hi/lo ----------------
// (R5-verified version, unchanged)
__global__ __launch_bounds__(256) void k_inter(
    const float* __restrict__ St, const float* __restrict__ Qg,
    const float* __restrict__ Yb, ushort* __restrict__ Yh,
    ushort* __restrict__ Yl) {
  const int c = blockIdx.x;
  const int b = blockIdx.y;
  const int z = blockIdx.z;
  const int t0 = c * 32;
  const int tid = threadIdx.x;
  __shared__ float Sts[64][68];
  __shared__ float Qs[32][68];
  {
    const size_t sb = ((size_t)b * 64 + c) * 4096;
#pragma unroll
    for (int g = 0; g < 4; ++g) {
      const int idx = g * 256 + tid;
      const int k = idx >> 4, n = (idx & 15) * 4;
      *(float4*)&Sts[k][n] = *(const float4*)&St[sb + (size_t)k * 64 + n];
    }
#pragma unroll
    for (int g = 0; g < 2; ++g) {
      const int idx = g * 256 + tid;
      const int r = idx >> 4, q = (idx & 15) * 4;
      *(float4*)&Qs[r][q] = *(const float4*)&Qg[(size_t)(b * TS + t0 + r) * KD + q];
    }
  }
  __syncthreads();

  const int nx = (tid & 15) * 4;
  const int tr = (tid >> 4) + z * 16;  // this block's 16-row half
  float y0[4] = {0.f, 0.f, 0.f, 0.f};
#pragma unroll
  for (int k = 0; k < 64; k += 4) {
    const float4 q0 = *(const float4*)&Qs[tr][k];
#pragma unroll
    for (int u = 0; u < 4; ++u) {
      const float4 s4 = *(const float4*)&Sts[k + u][nx];
      const float a0 = (u == 0) ? q0.x : (u == 1) ? q0.y : (u == 2) ? q0.z : q0.w;
      y0[0] += a0 * s4.x; y0[1] += a0 * s4.y; y0[2] += a0 * s4.z; y0[3] += a0 * s4.w;
    }
  }

  const size_t r0 = (size_t)(b * TS + t0 + tr) * KD + nx;
  float4 p0 = *(const float4*)&Yb[r0];
  p0.x += y0[0]; p0.y += y0[1]; p0.z += y0[2]; p0.w += y0[3];
  const ushort h00 = f2bf(p0.x), h01 = f2bf(p0.y), h02 = f2bf(p0.z), h03 = f2bf(p0.w);
  *(ushort4*)&Yh[r0] = make_ushort4(h00, h01, h02, h03);
  *(ushort4*)&Yl[r0] = make_ushort4(
      f2bf(p0.x - bf2f(h00)), f2bf(p0.y - bf2f(h01)),
      f2bf(p0.z - bf2f(h02)), f2bf(p0.w - bf2f(h03)));
}

// ---------------- C4: MFMA bf16x3 out-GEMM  out = Y @ Wo + bo ----------------
// 32-row M-tiles (grid 1024 blocks, 4 blk/CU, was 2): k_out is write-BW-bound
// (33.5 MB out at ~3 TB/s effective with only 2 blk/CU of store concurrency).
// Unlike R9's k_qkv split, NO staging is duplicated: WoT B-reads are 256 KB
// L2-hot, A-reads total the same, Cs is per-block scratch. Per-element MFMA
// chain, bias, and store addresses unchanged -> bit-identical output.
__global__ __launch_bounds__(256) void k_out(
    const ushort* __restrict__ Yh, const ushort* __restrict__ Yl,
    const ushort* __restrict__ Wh, const ushort* __restrict__ Wl,
    const float* __restrict__ bo, float* __restrict__ out) {
  const int m0 = blockIdx.x * 32;
  const int tid = threadIdx.x;
  const int wave = tid >> 6, lane = tid & 63;
  const int quad = lane >> 4, l15 = lane & 15;
  const int n0 = blockIdx.y * 256 + wave * 64;
  __shared__ float Cs[4][16][68];

  bf16x8 a_h[2][2], a_l[2][2];
#pragma unroll
  for (int mt = 0; mt < 2; ++mt)
#pragma unroll
    for (int kk = 0; kk < 2; ++kk) {
      const size_t off = (size_t)(m0 + mt * 16 + l15) * KD + kk * 32 + quad * 8;
      a_h[mt][kk] = *(const bf16x8*)&Yh[off];
      a_l[mt][kk] = *(const bf16x8*)&Yl[off];
    }

  f32x4 acc[2][4];
#pragma unroll
  for (int mt = 0; mt < 2; ++mt)
#pragma unroll
    for (int nt = 0; nt < 4; ++nt) acc[mt][nt] = (f32x4){0.f, 0.f, 0.f, 0.f};

#pragma unroll
  for (int nt = 0; nt < 4; ++nt) {
#pragma unroll
    for (int kk = 0; kk < 2; ++kk) {
      const size_t off = (size_t)(n0 + nt * 16 + l15) * KD + kk * 32 + quad * 8;
      const bf16x8 b_h = *(const bf16x8*)&Wh[off];
      const bf16x8 b_l = *(const bf16x8*)&Wl[off];
#pragma unroll
      for (int mt = 0; mt < 2; ++mt) {
        acc[mt][nt] = __builtin_amdgcn_mfma_f32_16x16x32_bf16(a_h[mt][kk], b_h, acc[mt][nt], 0, 0, 0);
        acc[mt][nt] = __builtin_amdgcn_mfma_f32_16x16x32_bf16(a_h[mt][kk], b_l, acc[mt][nt], 0, 0, 0);
        acc[mt][nt] = __builtin_amdgcn_mfma_f32_16x16x32_bf16(a_l[mt][kk], b_h, acc[mt][nt], 0, 0, 0);
      }
    }
  }

#pragma unroll
  for (int mt = 0; mt < 2; ++mt) {
#pragma unroll
    for (int nt = 0; nt < 4; ++nt)
#pragma unroll
      for (int r = 0; r < 4; ++r)
        Cs[wave][quad * 4 + r][nt * 16 + l15] = acc[mt][nt][r];
    __syncthreads();
#pragma unroll
    for (int i = 0; i < 4; ++i) {
      const int rr = i * 4 + (lane >> 4);
      const int cc = (lane & 15) * 4;
      float4 v = *(const float4*)&Cs[wave][rr][cc];
      const float4 b4 = *(const float4*)&bo[n0 + cc];
      v.x += b4.x; v.y += b4.y; v.z += b4.z; v.w += b4.w;
      *(float4*)&out[(size_t)(m0 + mt * 16 + rr) * DM + n0 + cc] = v;
    }
    __syncthreads();
  }
}

extern "C" void kernel_launch(void* const* d_in, const int* in_sizes, int n_in,
                              void* d_out, int out_size, void* d_ws, size_t ws_size,
                              hipStream_t stream) {
  const float* x     = (const float*)d_in[0];
  const float* W_pre = (const float*)d_in[1];
  const float* b_pre = (const float*)d_in[2];
  const float* Qf    = (const float*)d_in[3];
  const float* Kf    = (const float*)d_in[4];
  const float* W_v   = (const float*)d_in[5];
  const float* b_v   = (const float*)d_in[6];
  const float* W_o   = (const float*)d_in[7];
  const float* b_o   = (const float*)d_in[8];
  const float* decay = (const float*)d_in[9];
  float* out = (float*)d_out;
  float* ws = (float*)d_ws;

  ushort* WT_hi = (ushort*)(ws + WTH_OFF);
  ushort* WT_lo = (ushort*)(ws + WTL_OFF);
  float* bcomb = ws + BC_OFF;
  float* Qg    = ws + QG_OFF;
  float* P     = ws + P_OFF;
  float* Pf    = ws + PF_OFF;
  float* St    = ws + ST_OFF;
  float* O     = ws + O_OFF;
  float* Yb    = ws + YB_OFF;
  ushort* WoT_hi = (ushort*)(ws + WOTH_OFF);
  ushort* WoT_lo = (ushort*)(ws + WOTL_OFF);
  ushort* Yf_hi  = (ushort*)(ws + YFH_OFF);
  ushort* Yf_lo  = (ushort*)(ws + YFL_OFF);

  k_prep<<<dim3(16, 2, 16), 256, 0, stream>>>(W_pre, Qf, Kf, Pf);
  k_fred<<<dim3(64), 256, 0, stream>>>(Pf, W_v, b_pre, Qf, Kf, b_v, W_o,
                                       WT_hi, WT_lo, bcomb, WoT_hi, WoT_lo);
  k_qkv<<<dim3(NB * TS / 64, 4), 512, 0, stream>>>(x, WT_hi, WT_lo, P);
  k_chunkred<<<dim3(TS / 32, NB), 512, 0, stream>>>(P, bcomb, decay, Qg, Yb, O);
  k_scan<<<dim3(16, NB), 64, 0, stream>>>(O, St);
  k_inter<<<dim3(TS / 32, NB, 2), 256, 0, stream>>>(St, Qg, Yb, Yf_hi, Yf_lo);
  k_out<<<dim3(NB * TS / 32, 4), 256, 0, stream>>>(Yf_hi, Yf_lo, WoT_hi, WoT_lo,
                                                   b_o, out);
}

// Round 13
// 164.349 us; speedup vs baseline: 1.0297x; 1.0297x over previous
//
#include <hip/hip_runtime.h>

#define TS 2048   // seq len
#define DM 1024   // d_model
#define KD 64     // k
#define NB 4      // batch

// ---------- workspace layout (float offsets) ----------
// WT_hi [192][1024] ushort : rows 0-63 Wq^T, 64-127 Wk^T, 128-191 Wv^T (bf16 hi)
// WT_lo [192][1024] ushort : bf16 residual (lo)
// bcomb [192] f32          : bq | bk | bv
// Qg    [8192][64] f32     : Q-only (k_chunkred -> k_inter)
// P     [4][8192][192] f32 : split-K partials (k_qkv -> k_chunkred)
// Pf    [16][128][1024] f32: fold partials (k_prep -> k_fred), overlays P front
// St    [4][64][64][64] f32: exclusive chunk-prefix (k_scan -> k_inter),
//                            overlays dead P region (P consumed by k_chunkred)
// O     [4][64][64][64] f32: per-chunk outer sums (k_chunkred -> k_scan)
// Yb    [8192][64] f32     : intra-chunk Y (k_chunkred -> k_inter)
// WoT_hi/lo [1024][64] ushort : Wo^T bf16 hi/lo  (k_fred -> k_out)
// Yf_hi/lo  [8192][64] ushort : final Y bf16 hi/lo (k_inter -> k_out)
#define WTH_OFF 0
#define WTL_OFF 98304
#define BC_OFF  196608
#define QG_OFF  196864
#define P_OFF   1769728
#define PF_OFF  (P_OFF)
#define ST_OFF  (P_OFF)
#define O_OFF   8061184
#define YB_OFF  9109760
#define WOTH_OFF 9634048
#define WOTL_OFF 9666816
#define YFH_OFF  9699584
#define YFL_OFF  9961728

typedef __attribute__((ext_vector_type(8))) short bf16x8;
typedef __attribute__((ext_vector_type(4))) float f32x4;

__device__ __forceinline__ ushort f2bf(float f) {
  unsigned u = __float_as_uint(f);
  unsigned r = u + 0x7FFFu + ((u >> 16) & 1u);
  return (ushort)(r >> 16);
}
__device__ __forceinline__ float bf2f(ushort h) {
  return __uint_as_float(((unsigned)h) << 16);
}

// ---------------- A1: split-K MFMA fold partials ----------------
__global__ __launch_bounds__(256) void k_prep(
    const float* __restrict__ W_pre, const float* __restrict__ Qf,
    const float* __restrict__ Kf, float* __restrict__ Pf) {
  const int d0 = blockIdx.x * 64;
  const int f = blockIdx.y;
  const int ks = blockIdx.z;
  const float* __restrict__ F = f ? Kf : Qf;
  const int tid = threadIdx.x;
  const int wave = tid >> 6, lane = tid & 63;
  const int quad = lane >> 4, l15 = lane & 15;
  __shared__ ushort As[64 * 72];
  __shared__ ushort Bs[64 * 72];
  f32x4 acc[4];
#pragma unroll
  for (int nt = 0; nt < 4; ++nt) acc[nt] = (f32x4){0.f, 0.f, 0.f, 0.f};

  const int ra = tid >> 3;
  const int c4 = (tid & 7) * 4;
  float4 aw[2];
  float bw[8];
  int t0 = ks * 128;
#pragma unroll
  for (int i = 0; i < 2; ++i)
    aw[i] = *(const float4*)&W_pre[(size_t)(d0 + i * 32 + ra) * TS + t0 + c4];
#pragma unroll
  for (int h = 0; h < 2; ++h)
#pragma unroll
    for (int u = 0; u < 4; ++u)
      bw[h * 4 + u] = F[(size_t)(t0 + (wave + 4 * h) * 4 + u) * KD + lane];

  for (int step = 0; step < 4; ++step) {
    __syncthreads();
#pragma unroll
    for (int i = 0; i < 2; ++i) {
      const int r = i * 32 + ra;
      const float4 v = aw[i];
      const ushort h0 = f2bf(v.x), h1 = f2bf(v.y), h2 = f2bf(v.z), h3 = f2bf(v.w);
      *(ushort4*)&As[r * 72 + c4] = make_ushort4(h0, h1, h2, h3);
      *(ushort4*)&As[r * 72 + 32 + c4] = make_ushort4(
          f2bf(v.x - bf2f(h0)), f2bf(v.y - bf2f(h1)),
          f2bf(v.z - bf2f(h2)), f2bf(v.w - bf2f(h3)));
    }
#pragma unroll
    for (int h = 0; h < 2; ++h) {
      const int gg = wave + 4 * h;
      ushort hh[4], ll[4];
#pragma unroll
      for (int u = 0; u < 4; ++u) {
        hh[u] = f2bf(bw[h * 4 + u]);
        ll[u] = f2bf(bw[h * 4 + u] - bf2f(hh[u]));
      }
      *(ushort4*)&Bs[lane * 72 + gg * 4] = make_ushort4(hh[0], hh[1], hh[2], hh[3]);
      *(ushort4*)&Bs[lane * 72 + 32 + gg * 4] = make_ushort4(ll[0], ll[1], ll[2], ll[3]);
    }
    __syncthreads();
    if (step < 3) {
      const int t1 = t0 + 32;
#pragma unroll
      for (int i = 0; i < 2; ++i)
        aw[i] = *(const float4*)&W_pre[(size_t)(d0 + i * 32 + ra) * TS + t1 + c4];
#pragma unroll
      for (int h = 0; h < 2; ++h)
#pragma unroll
        for (int u = 0; u < 4; ++u)
          bw[h * 4 + u] = F[(size_t)(t1 + (wave + 4 * h) * 4 + u) * KD + lane];
    }
    const ushort* ap = &As[(wave * 16 + l15) * 72 + quad * 8];
    const bf16x8 a_h = *(const bf16x8*)ap;
    const bf16x8 a_l = *(const bf16x8*)(ap + 32);
#pragma unroll
    for (int nt = 0; nt < 4; ++nt) {
      const ushort* bp = &Bs[(nt * 16 + l15) * 72 + quad * 8];
      const bf16x8 b_h = *(const bf16x8*)bp;
      const bf16x8 b_l = *(const bf16x8*)(bp + 32);
      acc[nt] = __builtin_amdgcn_mfma_f32_16x16x32_bf16(a_h, b_h, acc[nt], 0, 0, 0);
      acc[nt] = __builtin_amdgcn_mfma_f32_16x16x32_bf16(a_h, b_l, acc[nt], 0, 0, 0);
      acc[nt] = __builtin_amdgcn_mfma_f32_16x16x32_bf16(a_l, b_h, acc[nt], 0, 0, 0);
    }
    t0 += 32;
  }
#pragma unroll
  for (int nt = 0; nt < 4; ++nt) {
    const int n = f * 64 + nt * 16 + l15;
#pragma unroll
    for (int r = 0; r < 4; ++r) {
      const int d = d0 + wave * 16 + quad * 4 + r;
      Pf[((size_t)ks * 128 + n) * DM + d] = acc[nt][r];
    }
  }
}

// ---------------- A2: reduce fold partials -> WT hi/lo; Wv transpose; bias;
// ----------------     Wo transpose -> WoT hi/lo ----------------
__global__ __launch_bounds__(256) void k_fred(
    const float* __restrict__ Pf, const float* __restrict__ Wv,
    const float* __restrict__ b_pre, const float* __restrict__ Qf,
    const float* __restrict__ Kf, const float* __restrict__ bv,
    const float* __restrict__ Wo,
    ushort* __restrict__ WT_hi, ushort* __restrict__ WT_lo,
    float* __restrict__ bcomb,
    ushort* __restrict__ WoT_hi, ushort* __restrict__ WoT_lo) {
  const int bx = blockIdx.x;
  const int tid = threadIdx.x;
  if (bx < 32) {
    const int n0 = bx * 4;
    const int d4 = tid * 4;
#pragma unroll
    for (int j = 0; j < 4; ++j) {
      const int n = n0 + j;
      float4 s = {0.f, 0.f, 0.f, 0.f};
#pragma unroll
      for (int ks = 0; ks < 16; ++ks) {
        const float4 v = *(const float4*)&Pf[((size_t)ks * 128 + n) * DM + d4];
        s.x += v.x; s.y += v.y; s.z += v.z; s.w += v.w;
      }
      const ushort h0 = f2bf(s.x), h1 = f2bf(s.y), h2 = f2bf(s.z), h3 = f2bf(s.w);
      *(ushort4*)&WT_hi[(size_t)n * DM + d4] = make_ushort4(h0, h1, h2, h3);
      *(ushort4*)&WT_lo[(size_t)n * DM + d4] = make_ushort4(
          f2bf(s.x - bf2f(h0)), f2bf(s.y - bf2f(h1)),
          f2bf(s.z - bf2f(h2)), f2bf(s.w - bf2f(h3)));
    }
    const float* __restrict__ F = (n0 < 64) ? Qf : Kf;
    const int c0 = n0 & 63;
    __shared__ float bred[4][256];
    float p[4] = {0.f, 0.f, 0.f, 0.f};
#pragma unroll
    for (int u = 0; u < 8; ++u) {
      const int t = tid * 8 + u;
      const float bp = b_pre[t];
#pragma unroll
      for (int j = 0; j < 4; ++j) p[j] += bp * F[(size_t)t * KD + c0 + j];
    }
#pragma unroll
    for (int j = 0; j < 4; ++j) bred[j][tid] = p[j];
    __syncthreads();
    for (int s = 128; s > 0; s >>= 1) {
      if (tid < s) {
#pragma unroll
        for (int j = 0; j < 4; ++j) bred[j][tid] += bred[j][tid + s];
      }
      __syncthreads();
    }
    if (tid < 4) bcomb[n0 + tid] = bred[tid][0];
  } else if (bx < 48) {
    const int n0 = 128 + (bx - 32) * 4;
    const int d4 = tid * 4;
#pragma unroll
    for (int j = 0; j < 4; ++j) {
      const int c = n0 - 128 + j;
      float v[4];
#pragma unroll
      for (int i = 0; i < 4; ++i) v[i] = Wv[(size_t)(d4 + i) * KD + c];
      const ushort h0 = f2bf(v[0]), h1 = f2bf(v[1]), h2 = f2bf(v[2]), h3 = f2bf(v[3]);
      *(ushort4*)&WT_hi[(size_t)(n0 + j) * DM + d4] = make_ushort4(h0, h1, h2, h3);
      *(ushort4*)&WT_lo[(size_t)(n0 + j) * DM + d4] = make_ushort4(
          f2bf(v[0] - bf2f(h0)), f2bf(v[1] - bf2f(h1)),
          f2bf(v[2] - bf2f(h2)), f2bf(v[3] - bf2f(h3)));
    }
    if (tid < 4) bcomb[n0 + tid] = bv[n0 - 128 + tid];
  } else {
    // Wo [64][1024] -> WoT [1024][64] bf16 hi/lo
    const int d0 = (bx - 48) * 64;
    const int d = d0 + (tid >> 2);
    const int k0 = (tid & 3) * 16;
#pragma unroll
    for (int u = 0; u < 16; ++u) {
      const int k = k0 + u;
      const float v = Wo[(size_t)k * DM + d];
      const ushort h = f2bf(v);
      WoT_hi[(size_t)d * KD + k] = h;
      WoT_lo[(size_t)d * KD + k] = f2bf(v - bf2f(h));
    }
  }
}

// ---------------- B: split-K MFMA bf16x3 GEMM  P[ks] = x[:, ks*256:+256] @ W ----------------
// (R8/R10-verified: 64-row tile, 512 threads / 8 waves, LDS-transpose epilogue)
__global__ __launch_bounds__(512) void k_qkv(
    const float* __restrict__ x, const ushort* __restrict__ WT_hi,
    const ushort* __restrict__ WT_lo, float* __restrict__ P) {
  const int row0 = blockIdx.x * 64;
  const int ks = blockIdx.y;
  const int tid = threadIdx.x;
  const int wave = tid >> 6, lane = tid & 63;
  const int quad = lane >> 4, l15 = lane & 15;
  const int wm = wave >> 2;   // 0..1 : 32-row half
  const int wn = wave & 3;    // 0..3 : 48-col slice
  const int n0 = wn * 48;
  __shared__ ushort As[64 * 72];
  __shared__ ushort Bs[192 * 72];
  __shared__ float Cs[16][196];
  f32x4 acc[2][3];
#pragma unroll
  for (int mt = 0; mt < 2; ++mt)
#pragma unroll
    for (int nt = 0; nt < 3; ++nt) acc[mt][nt] = (f32x4){0.f, 0.f, 0.f, 0.f};

  for (int step = 0; step < 8; ++step) {
    const int kk = ks * 256 + step * 32;
    __syncthreads();
    {
      // A-tile: 64 rows x 32 cols = 512 float4, one per thread
      const int r = tid >> 3, c4 = (tid & 7) * 4;
      const float4 v = *(const float4*)&x[(size_t)(row0 + r) * DM + kk + c4];
      const ushort h0 = f2bf(v.x), h1 = f2bf(v.y), h2 = f2bf(v.z), h3 = f2bf(v.w);
      *(ushort4*)&As[r * 72 + c4] = make_ushort4(h0, h1, h2, h3);
      *(ushort4*)&As[r * 72 + 32 + c4] = make_ushort4(
          f2bf(v.x - bf2f(h0)), f2bf(v.y - bf2f(h1)),
          f2bf(v.z - bf2f(h2)), f2bf(v.w - bf2f(h3)));
    }
#pragma unroll
    for (int i = 0; i < 3; ++i) {
      // B-tile: 1536 float4 over 512 threads
      const int idx = i * 512 + tid;
      const int half = idx >= 768;
      const int j = half ? idx - 768 : idx;
      const int n = j >> 2, ch = j & 3;
      const ushort* src = (half ? WT_lo : WT_hi) + (size_t)n * DM + kk + ch * 8;
      *(float4*)&Bs[n * 72 + half * 32 + ch * 8] = *(const float4*)src;
    }
    __syncthreads();
    bf16x8 a_h[2], a_l[2], b_h[3], b_l[3];
#pragma unroll
    for (int mt = 0; mt < 2; ++mt) {
      const ushort* p = &As[(wm * 32 + mt * 16 + l15) * 72 + quad * 8];
      a_h[mt] = *(const bf16x8*)p;
      a_l[mt] = *(const bf16x8*)(p + 32);
    }
#pragma unroll
    for (int nt = 0; nt < 3; ++nt) {
      const ushort* p = &Bs[(n0 + nt * 16 + l15) * 72 + quad * 8];
      b_h[nt] = *(const bf16x8*)p;
      b_l[nt] = *(const bf16x8*)(p + 32);
    }
#pragma unroll
    for (int mt = 0; mt < 2; ++mt)
#pragma unroll
      for (int nt = 0; nt < 3; ++nt) {
        acc[mt][nt] = __builtin_amdgcn_mfma_f32_16x16x32_bf16(a_h[mt], b_h[nt], acc[mt][nt], 0, 0, 0);
        acc[mt][nt] = __builtin_amdgcn_mfma_f32_16x16x32_bf16(a_h[mt], b_l[nt], acc[mt][nt], 0, 0, 0);
        acc[mt][nt] = __builtin_amdgcn_mfma_f32_16x16x32_bf16(a_l[mt], b_h[nt], acc[mt][nt], 0, 0, 0);
      }
  }
  // LDS-transpose epilogue: per 16-row chunk (owned by wave-half wm==mtg>>1),
  // stage acc -> Cs, then all 512 threads write full 768 B contiguous rows.
  float* Pp = P + (size_t)ks * TS * NB * 192;
#pragma unroll
  for (int mtg = 0; mtg < 4; ++mtg) {
    __syncthreads();
    if (wm == (mtg >> 1)) {
      const int mt = mtg & 1;
#pragma unroll
      for (int nt = 0; nt < 3; ++nt)
#pragma unroll
        for (int r = 0; r < 4; ++r)
          Cs[quad * 4 + r][n0 + nt * 16 + l15] = acc[mt][nt][r];
    }
    __syncthreads();
    // 16 rows x 48 float4 = 768 float4 over 512 threads
#pragma unroll
    for (int it = 0; it < 2; ++it) {
      const int idx = it * 512 + tid;
      if (idx < 768) {
        const int r = idx / 48, c4 = (idx % 48) * 4;
        *(float4*)&Pp[(size_t)(row0 + mtg * 16 + r) * 192 + c4] =
            *(const float4*)&Cs[r][c4];
      }
    }
  }
}

// ---------------- C1: fused split-K reduce + per-chunk intra + outer sums ----------------
// (R11-verified: 512 threads, Ss/Yb chain on waves 0-3, O chain on waves 4-7)
__global__ __launch_bounds__(512) void k_chunkred(
    const float* __restrict__ P, const float* __restrict__ bcomb,
    const float* __restrict__ decay, float* __restrict__ Qg,
    float* __restrict__ Yb, float* __restrict__ O) {
  const int c = blockIdx.x;
  const int b = blockIdx.y;
  const int s0 = c * 32;
  const int tid = threadIdx.x;
  __shared__ float Qs[32][68], Ks[32][68], Vs[32][68];
  __shared__ float Ss[32][36];
  __shared__ float dec[32];
  const size_t NTOT = (size_t)TS * NB * 192;

  for (int idx = tid; idx < 32 * 48; idx += 512) {
    const int r = idx / 48, cq = (idx % 48) * 4;
    const size_t g = (size_t)(b * TS + s0 + r) * 192 + cq;
    float4 a = *(const float4*)&P[g];
    const float4 b2 = *(const float4*)&P[NTOT + g];
    const float4 c2 = *(const float4*)&P[2 * NTOT + g];
    const float4 d2 = *(const float4*)&P[3 * NTOT + g];
    const float4 bi = *(const float4*)&bcomb[cq];
    a.x += b2.x + c2.x + d2.x + bi.x;
    a.y += b2.y + c2.y + d2.y + bi.y;
    a.z += b2.z + c2.z + d2.z + bi.z;
    a.w += b2.w + c2.w + d2.w + bi.w;
    if (cq < 64) {
      *(float4*)&Qs[r][cq] = a;
      *(float4*)&Qg[(size_t)(b * TS + s0 + r) * KD + cq] = a;
    } else if (cq < 128) {
      *(float4*)&Ks[r][cq - 64] = a;
    } else {
      *(float4*)&Vs[r][cq - 128] = a;
    }
  }
  if (tid < 32) dec[tid] = decay[s0 + tid];
  __syncthreads();

  float o[4][4];
  if (tid < 256) {
    const int sc = (tid & 15) * 2;
    const int tr = (tid >> 4) * 2;
    float a00 = 0.f, a01 = 0.f, a10 = 0.f, a11 = 0.f;
#pragma unroll
    for (int k = 0; k < 64; k += 4) {
      const float4 q0 = *(const float4*)&Qs[tr][k];
      const float4 q1 = *(const float4*)&Qs[tr + 1][k];
      const float4 v0 = *(const float4*)&Vs[sc][k];
      const float4 v1 = *(const float4*)&Vs[sc + 1][k];
      a00 += q0.x * v0.x + q0.y * v0.y + q0.z * v0.z + q0.w * v0.w;
      a01 += q0.x * v1.x + q0.y * v1.y + q0.z * v1.z + q0.w * v1.w;
      a10 += q1.x * v0.x + q1.y * v0.y + q1.z * v0.z + q1.w * v0.w;
      a11 += q1.x * v1.x + q1.y * v1.y + q1.z * v1.z + q1.w * v1.w;
    }
    const float d0 = dec[sc], d1 = dec[sc + 1];
    Ss[tr][sc]         = (sc     <= tr)     ? a00 * d0 : 0.f;
    Ss[tr][sc + 1]     = (sc + 1 <= tr)     ? a01 * d1 : 0.f;
    Ss[tr + 1][sc]     = (sc     <= tr + 1) ? a10 * d0 : 0.f;
    Ss[tr + 1][sc + 1] = (sc + 1 <= tr + 1) ? a11 * d1 : 0.f;
  } else {
    const int t2 = tid - 256;
#pragma unroll
    for (int i = 0; i < 4; ++i)
#pragma unroll
      for (int j = 0; j < 4; ++j) o[i][j] = 0.f;
    const int kx = (t2 & 15) * 4;
    const int nx = (t2 >> 4) * 4;
#pragma unroll
    for (int s = 0; s < 32; ++s) {
      const float ds = dec[s];
      float4 v4 = *(const float4*)&Vs[s][kx];
      const float4 k4 = *(const float4*)&Ks[s][nx];
      v4.x *= ds; v4.y *= ds; v4.z *= ds; v4.w *= ds;
      o[0][0] += v4.x * k4.x; o[0][1] += v4.x * k4.y; o[0][2] += v4.x * k4.z; o[0][3] += v4.x * k4.w;
      o[1][0] += v4.y * k4.x; o[1][1] += v4.y * k4.y; o[1][2] += v4.y * k4.z; o[1][3] += v4.y * k4.w;
      o[2][0] += v4.z * k4.x; o[2][1] += v4.z * k4.y; o[2][2] += v4.z * k4.z; o[2][3] += v4.z * k4.w;
      o[3][0] += v4.w * k4.x; o[3][1] += v4.w * k4.y; o[3][2] += v4.w * k4.z; o[3][3] += v4.w * k4.w;
    }
  }
  __syncthreads();

  if (tid < 256) {
    const int nx = (tid & 15) * 4;
    const int tr = (tid >> 4) * 2;
    float y0[4] = {0.f, 0.f, 0.f, 0.f};
    float y1[4] = {0.f, 0.f, 0.f, 0.f};
#pragma unroll
    for (int s = 0; s < 32; s += 4) {
      const float4 sa = *(const float4*)&Ss[tr][s];
      const float4 sb = *(const float4*)&Ss[tr + 1][s];
#pragma unroll
      for (int u = 0; u < 4; ++u) {
        const float4 k4 = *(const float4*)&Ks[s + u][nx];
        const float su0 = (u == 0) ? sa.x : (u == 1) ? sa.y : (u == 2) ? sa.z : sa.w;
        const float su1 = (u == 0) ? sb.x : (u == 1) ? sb.y : (u == 2) ? sb.z : sb.w;
        y0[0] += su0 * k4.x; y0[1] += su0 * k4.y; y0[2] += su0 * k4.z; y0[3] += su0 * k4.w;
        y1[0] += su1 * k4.x; y1[1] += su1 * k4.y; y1[2] += su1 * k4.z; y1[3] += su1 * k4.w;
      }
    }
    float4 w0, w1;
    w0.x = y0[0]; w0.y = y0[1]; w0.z = y0[2]; w0.w = y0[3];
    w1.x = y1[0]; w1.y = y1[1]; w1.z = y1[2]; w1.w = y1[3];
    *(float4*)&Yb[(size_t)(b * TS + s0 + tr) * KD + nx] = w0;
    *(float4*)&Yb[(size_t)(b * TS + s0 + tr + 1) * KD + nx] = w1;
  } else {
    const int t2 = tid - 256;
    const int kx = (t2 & 15) * 4;
    const int nx = (t2 >> 4) * 4;
    const size_t base = ((size_t)(b * 64 + c) * 64) * 64;
#pragma unroll
    for (int i = 0; i < 4; ++i) {
      float4 w;
      w.x = o[i][0]; w.y = o[i][1]; w.z = o[i][2]; w.w = o[i][3];
      *(float4*)&O[base + (size_t)(kx + i) * 64 + nx] = w;
    }
  }
}

// ---------------- C2: exclusive prefix over chunks (O -> St) ----------------
__global__ __launch_bounds__(64) void k_scan(const float* __restrict__ O,
                                             float* __restrict__ St) {
  const int e4 = (blockIdx.x * 64 + threadIdx.x) * 4;
  const int b = blockIdx.y;
  const float* op = O + (size_t)b * 64 * 4096 + e4;
  float* sp = St + (size_t)b * 64 * 4096 + e4;
  float4 run = {0.f, 0.f, 0.f, 0.f};
#pragma unroll
  for (int cg = 0; cg < 8; ++cg) {
    float4 v[8];
#pragma unroll
    for (int u = 0; u < 8; ++u)
      v[u] = *(const float4*)&op[(size_t)(cg * 8 + u) * 4096];
#pragma unroll
    for (int u = 0; u < 8; ++u) {
      *(float4*)&sp[(size_t)(cg * 8 + u) * 4096] = run;
      run.x += v[u].x; run.y += v[u].y; run.z += v[u].z; run.w += v[u].w;
    }
  }
}

// ---------------- C3: inter-chunk attention, emit Y as bf16 hi/lo ----------------
// (R5-verified version, unchanged)
__global__ __launch_bounds__(256) void k_inter(
    const float* __restrict__ St, const float* __restrict__ Qg,
    const float* __restrict__ Yb, ushort* __restrict__ Yh,
    ushort* __restrict__ Yl) {
  const int c = blockIdx.x;
  const int b = blockIdx.y;
  const int z = blockIdx.z;
  const int t0 = c * 32;
  const int tid = threadIdx.x;
  __shared__ float Sts[64][68];
  __shared__ float Qs[32][68];
  {
    const size_t sb = ((size_t)b * 64 + c) * 4096;
#pragma unroll
    for (int g = 0; g < 4; ++g) {
      const int idx = g * 256 + tid;
      const int k = idx >> 4, n = (idx & 15) * 4;
      *(float4*)&Sts[k][n] = *(const float4*)&St[sb + (size_t)k * 64 + n];
    }
#pragma unroll
    for (int g = 0; g < 2; ++g) {
      const int idx = g * 256 + tid;
      const int r = idx >> 4, q = (idx & 15) * 4;
      *(float4*)&Qs[r][q] = *(const float4*)&Qg[(size_t)(b * TS + t0 + r) * KD + q];
    }
  }
  __syncthreads();

  const int nx = (tid & 15) * 4;
  const int tr = (tid >> 4) + z * 16;  // this block's 16-row half
  float y0[4] = {0.f, 0.f, 0.f, 0.f};
#pragma unroll
  for (int k = 0; k < 64; k += 4) {
    const float4 q0 = *(const float4*)&Qs[tr][k];
#pragma unroll
    for (int u = 0; u < 4; ++u) {
      const float4 s4 = *(const float4*)&Sts[k + u][nx];
      const float a0 = (u == 0) ? q0.x : (u == 1) ? q0.y : (u == 2) ? q0.z : q0.w;
      y0[0] += a0 * s4.x; y0[1] += a0 * s4.y; y0[2] += a0 * s4.z; y0[3] += a0 * s4.w;
    }
  }

  const size_t r0 = (size_t)(b * TS + t0 + tr) * KD + nx;
  float4 p0 = *(const float4*)&Yb[r0];
  p0.x += y0[0]; p0.y += y0[1]; p0.z += y0[2]; p0.w += y0[3];
  const ushort h00 = f2bf(p0.x), h01 = f2bf(p0.y), h02 = f2bf(p0.z), h03 = f2bf(p0.w);
  *(ushort4*)&Yh[r0] = make_ushort4(h00, h01, h02, h03);
  *(ushort4*)&Yl[r0] = make_ushort4(
      f2bf(p0.x - bf2f(h00)), f2bf(p0.y - bf2f(h01)),
      f2bf(p0.z - bf2f(h02)), f2bf(p0.w - bf2f(h03)));
}

// ---------------- C4: MFMA bf16x3 out-GEMM  out = Y @ Wo + bo ----------------
// (R11-verified 64-row version. R12's 32-row split regressed: it doubles
// per-output B-frag reads + epilogue overhead — same failure mode as R9.)
__global__ __launch_bounds__(256) void k_out(
    const ushort* __restrict__ Yh, const ushort* __restrict__ Yl,
    const ushort* __restrict__ Wh, const ushort* __restrict__ Wl,
    const float* __restrict__ bo, float* __restrict__ out) {
  const int m0 = blockIdx.x * 64;
  const int tid = threadIdx.x;
  const int wave = tid >> 6, lane = tid & 63;
  const int quad = lane >> 4, l15 = lane & 15;
  const int n0 = blockIdx.y * 256 + wave * 64;
  __shared__ float Cs[4][16][68];

  bf16x8 a_h[4][2], a_l[4][2];
#pragma unroll
  for (int mt = 0; mt < 4; ++mt)
#pragma unroll
    for (int kk = 0; kk < 2; ++kk) {
      const size_t off = (size_t)(m0 + mt * 16 + l15) * KD + kk * 32 + quad * 8;
      a_h[mt][kk] = *(const bf16x8*)&Yh[off];
      a_l[mt][kk] = *(const bf16x8*)&Yl[off];
    }

  f32x4 acc[4][4];
#pragma unroll
  for (int mt = 0; mt < 4; ++mt)
#pragma unroll
    for (int nt = 0; nt < 4; ++nt) acc[mt][nt] = (f32x4){0.f, 0.f, 0.f, 0.f};

#pragma unroll
  for (int nt = 0; nt < 4; ++nt) {
#pragma unroll
    for (int kk = 0; kk < 2; ++kk) {
      const size_t off = (size_t)(n0 + nt * 16 + l15) * KD + kk * 32 + quad * 8;
      const bf16x8 b_h = *(const bf16x8*)&Wh[off];
      const bf16x8 b_l = *(const bf16x8*)&Wl[off];
#pragma unroll
      for (int mt = 0; mt < 4; ++mt) {
        acc[mt][nt] = __builtin_amdgcn_mfma_f32_16x16x32_bf16(a_h[mt][kk], b_h, acc[mt][nt], 0, 0, 0);
        acc[mt][nt] = __builtin_amdgcn_mfma_f32_16x16x32_bf16(a_h[mt][kk], b_l, acc[mt][nt], 0, 0, 0);
        acc[mt][nt] = __builtin_amdgcn_mfma_f32_16x16x32_bf16(a_l[mt][kk], b_h, acc[mt][nt], 0, 0, 0);
      }
    }
  }

#pragma unroll
  for (int mt = 0; mt < 4; ++mt) {
#pragma unroll
    for (int nt = 0; nt < 4; ++nt)
#pragma unroll
      for (int r = 0; r < 4; ++r)
        Cs[wave][quad * 4 + r][nt * 16 + l15] = acc[mt][nt][r];
    __syncthreads();
#pragma unroll
    for (int i = 0; i < 4; ++i) {
      const int rr = i * 4 + (lane >> 4);
      const int cc = (lane & 15) * 4;
      float4 v = *(const float4*)&Cs[wave][rr][cc];
      const float4 b4 = *(const float4*)&bo[n0 + cc];
      v.x += b4.x; v.y += b4.y; v.z += b4.z; v.w += b4.w;
      *(float4*)&out[(size_t)(m0 + mt * 16 + rr) * DM + n0 + cc] = v;
    }
    __syncthreads();
  }
}

extern "C" void kernel_launch(void* const* d_in, const int* in_sizes, int n_in,
                              void* d_out, int out_size, void* d_ws, size_t ws_size,
                              hipStream_t stream) {
  const float* x     = (const float*)d_in[0];
  const float* W_pre = (const float*)d_in[1];
  const float* b_pre = (const float*)d_in[2];
  const float* Qf    = (const float*)d_in[3];
  const float* Kf    = (const float*)d_in[4];
  const float* W_v   = (const float*)d_in[5];
  const float* b_v   = (const float*)d_in[6];
  const float* W_o   = (const float*)d_in[7];
  const float* b_o   = (const float*)d_in[8];
  const float* decay = (const float*)d_in[9];
  float* out = (float*)d_out;
  float* ws = (float*)d_ws;

  ushort* WT_hi = (ushort*)(ws + WTH_OFF);
  ushort* WT_lo = (ushort*)(ws + WTL_OFF);
  float* bcomb = ws + BC_OFF;
  float* Qg    = ws + QG_OFF;
  float* P     = ws + P_OFF;
  float* Pf    = ws + PF_OFF;
  float* St    = ws + ST_OFF;
  float* O     = ws + O_OFF;
  float* Yb    = ws + YB_OFF;
  ushort* WoT_hi = (ushort*)(ws + WOTH_OFF);
  ushort* WoT_lo = (ushort*)(ws + WOTL_OFF);
  ushort* Yf_hi  = (ushort*)(ws + YFH_OFF);
  ushort* Yf_lo  = (ushort*)(ws + YFL_OFF);

  k_prep<<<dim3(16, 2, 16), 256, 0, stream>>>(W_pre, Qf, Kf, Pf);
  k_fred<<<dim3(64), 256, 0, stream>>>(Pf, W_v, b_pre, Qf, Kf, b_v, W_o,
                                       WT_hi, WT_lo, bcomb, WoT_hi, WoT_lo);
  k_qkv<<<dim3(NB * TS / 64, 4), 512, 0, stream>>>(x, WT_hi, WT_lo, P);
  k_chunkred<<<dim3(TS / 32, NB), 512, 0, stream>>>(P, bcomb, decay, Qg, Yb, O);
  k_scan<<<dim3(16, NB), 64, 0, stream>>>(O, St);
  k_inter<<<dim3(TS / 32, NB, 2), 256, 0, stream>>>(St, Qg, Yb, Yf_hi, Yf_lo);
  k_out<<<dim3(NB * TS / 64, 4), 256, 0, stream>>>(Yf_hi, Yf_lo, WoT_hi, WoT_lo,
                                                   b_o, out);
}